// Round 8
// baseline (237.826 us; speedup 1.0000x reference)
//
#include <hip/hip_runtime.h>

// VQ-VAE vector quantizer, MI355X (gfx950).
// Round 13: r11's structure (32 pts/wave + code-half split) at 256 thr/block.
//  - r12 lesson: occupancy was GRID-limited (512 blocks = 2/CU = 8 waves/CU,
//    latency-bound). Block = 64 pts x 4 waves (2 pt-groups x 2 code-halves)
//    -> grid 1024 = 4 blocks/CU = 16 waves/CU AND reads/MFMA = 1/2.
//  - launch_bounds(256,4) caps 128 VGPR; (bestk,seck) packed into one reg
//    per slot (bksk; lt1-update (bksk<<16)|k realizes sk<-bk) -> ~120 peak.
//  - Dispatches 7 -> 5: fixup_full now self-contained (per-row full rescan
//    writes codes+loss+row directly; scratch/atomicMin/fixup_write dropped);
//    small_gather + finalize merged.
//
// d_out scratch (bytes, consumed before gather_finalize / overwritten later):
//   [0,524288) cbh_perm | [524288,786432) bv2a | [786432,1048576) bvfa
//   [1572864,1835008) flagf
// d_ws: [0,2048) double loss_slots[256]; [2048,2052) cnt2; [2052,2056) cntf;
//       [4096,8192) float Bf[1024]; [8192,270336) uint flag2 (n | seck<<16)

#define N_PTS    65536
#define K_CODES  1024
#define DIM      256
#define MARGIN   1.5e-4f
#define WSKIP    4096

#define OUT_VALS  16777216
#define OUT_CODES 65536

typedef __attribute__((ext_vector_type(8))) short short8v;
typedef __attribute__((ext_vector_type(8))) _Float16 half8v;
typedef __attribute__((ext_vector_type(4))) float float4v;

// perm index (in shorts) for codebook element (r=code, k=dim):
// chunk = ((r>>4)*8 + (k>>5))*4 + ((k>>3)&3); idx = chunk*128 + (r&15)*8 + (k&7)
__device__ __forceinline__ int perm_idx(int r, int k) {
  return ((((r >> 4) * 8 + (k >> 5)) * 4 + ((k >> 3) & 3)) * 128) + (r & 15) * 8 + (k & 7);
}

__device__ __forceinline__ short f2h_bits(float x) {
  union { _Float16 h; short s; } u;
  u.h = (_Float16)x;              // v_cvt_f16_f32, RTE
  return u.s;
}

__device__ __forceinline__ void gload16(const void* g, void* l) {
  __builtin_amdgcn_global_load_lds(
      (const __attribute__((address_space(1))) unsigned*)g,
      (__attribute__((address_space(3))) unsigned*)l, 16, 0, 0);
}

// one wave per code row: Bf[r] = fl32(fp64 sum sq of ORIGINAL cb); emit
// fp16(1024*cb) in B-fragment-permuted order. Also zero ws header.
__global__ void prep_cb_kernel(const float* __restrict__ cb,
                               short* __restrict__ cbh_perm,
                               float* __restrict__ Bf,
                               unsigned long long* __restrict__ ws0) {
  const int gid = blockIdx.x * 256 + threadIdx.x;
  if (gid < 512) ws0[gid] = 0ull;             // loss_slots + cnt2/cntf
  int r    = blockIdx.x * 4 + (threadIdx.x >> 6);
  int lane = threadIdx.x & 63;
  const float4 v = *(const float4*)(cb + (size_t)r * DIM + lane * 4);
  double s = (double)v.x * v.x + (double)v.y * v.y
           + (double)v.z * v.z + (double)v.w * v.w;
#pragma unroll
  for (int off = 32; off > 0; off >>= 1) s += __shfl_down(s, off);
  if (lane == 0) Bf[r] = (float)s;
  short4 h = make_short4(f2h_bits(v.x * 1024.0f), f2h_bits(v.y * 1024.0f),
                         f2h_bits(v.z * 1024.0f), f2h_bits(v.w * 1024.0f));
  *(short4*)(cbh_perm + perm_idx(r, lane * 4)) = h;   // 8B aligned
}

// 1024 blocks x 256 thr (4 waves). Block: 64 points x all 1024 codes.
// Wave (wp = w>>1, h = w&1): points [m0 + wp*32, +32), codes [h*512, +512).
// 16-code tiles per half, double-buffered via global_load_lds.
__global__ __launch_bounds__(256, 4) void argmin_mfma_kernel(
    const float* __restrict__ z, const float* __restrict__ cb,
    const short* __restrict__ cbh_perm,
    const float* __restrict__ Bf, float* __restrict__ outq,
    float* __restrict__ codes_out,
    int* __restrict__ cnt2, int* __restrict__ cntf,
    unsigned* __restrict__ flag2, int* __restrict__ flagf,
    float* __restrict__ bv2a, float* __restrict__ bvfa,
    double* __restrict__ loss_slots) {
  __shared__ __align__(16) short lbuf[2][2][4096];  // [half][buf][16c x 256d]
  __shared__ float mv1[64][2], mv2[64][2], mv3[64][2];
  __shared__ int   mk1[64][2], mk2[64][2];
  __shared__ float mz[64];
  __shared__ int   scodes[64];
  const int t    = threadIdx.x;
  const int w    = t >> 6;
  const int l    = t & 63;
  const int quad = l >> 4;
  const int lr   = l & 15;
  const int wp   = w >> 1;          // point group 0..1
  const int h    = w & 1;           // code half
  const int m0   = blockIdx.x * 64;
  const int pbase = m0 + wp * 32;

  // stage tile 0 of this half early; wave covers bytes [wp*4096, +4096)
  {
    const char* src = (const char*)cbh_perm + (size_t)(h * 32) * 8192 + wp * 4096;
    char* dst = (char*)&lbuf[h][0][0] + wp * 4096;
#pragma unroll
    for (int i = 0; i < 4; ++i)
      gload16(src + i * 1024 + l * 16, dst + i * 1024 + l * 16);
  }

  // A-fragments for 2 x 16 rows + fp64 row sums of squares.
  half8v ah[2][8];
  float Szrow[2];
#pragma unroll
  for (int a = 0; a < 2; ++a) {
    const float* zrow = z + (size_t)(pbase + a * 16 + lr) * DIM;
    double zs = 0.0;
#pragma unroll
    for (int q = 0; q < 8; ++q) {
      float4 p0 = *(const float4*)(zrow + q * 32 + quad * 8);
      float4 p1 = *(const float4*)(zrow + q * 32 + quad * 8 + 4);
      zs = fma((double)p0.x, (double)p0.x, zs);
      zs = fma((double)p0.y, (double)p0.y, zs);
      zs = fma((double)p0.z, (double)p0.z, zs);
      zs = fma((double)p0.w, (double)p0.w, zs);
      zs = fma((double)p1.x, (double)p1.x, zs);
      zs = fma((double)p1.y, (double)p1.y, zs);
      zs = fma((double)p1.z, (double)p1.z, zs);
      zs = fma((double)p1.w, (double)p1.w, zs);
      half8v hh;
      hh[0] = (_Float16)p0.x; hh[1] = (_Float16)p0.y;
      hh[2] = (_Float16)p0.z; hh[3] = (_Float16)p0.w;
      hh[4] = (_Float16)p1.x; hh[5] = (_Float16)p1.y;
      hh[6] = (_Float16)p1.z; hh[7] = (_Float16)p1.w;
      ah[a][q] = hh;
    }
    zs += __shfl_xor(zs, 16);
    zs += __shfl_xor(zs, 32);
    Szrow[a] = (float)zs;          // lane l: ||z[pbase + a*16 + (l&15)]||^2
  }

  // top-3 values + packed (bestk | seck<<16) per slot s = a*4 + r
  float bv[8], sv[8], tv[8]; unsigned bksk[8];
#pragma unroll
  for (int s = 0; s < 8; ++s) {
    bv[s] = 3.0e38f; sv[s] = 3.0e38f; tv[s] = 3.0e38f; bksk[s] = 0u;
  }

  __syncthreads();          // tile 0 resident
  int cur = 0;
  for (int it = 0; it < 32; ++it) {
    if (it < 31) {          // prefetch next 16-code tile of this half
      const char* src = (const char*)cbh_perm + (size_t)(h * 32 + it + 1) * 8192 + wp * 4096;
      char* dst = (char*)&lbuf[h][cur ^ 1][0] + wp * 4096;
#pragma unroll
      for (int i = 0; i < 4; ++i)
        gload16(src + i * 1024 + l * 16, dst + i * 1024 + l * 16);
    }
    const short* bb = &lbuf[h][cur][0];
    float4v acc0 = {0.f, 0.f, 0.f, 0.f};
    float4v acc1 = {0.f, 0.f, 0.f, 0.f};
#pragma unroll
    for (int q = 0; q < 8; ++q) {
      half8v b = *(const half8v*)(bb + q * 512 + quad * 128 + lr * 8);
      acc0 = __builtin_amdgcn_mfma_f32_16x16x32_f16(ah[0][q], b, acc0, 0, 0, 0);
      acc1 = __builtin_amdgcn_mfma_f32_16x16x32_f16(ah[1][q], b, acc1, 0, 0, 0);
    }
    const int k = (h * 32 + it) * 16 + lr;   // this lane's code (C col = lr)
    const float bkf = Bf[k];
#pragma unroll
    for (int a = 0; a < 2; ++a) {
#pragma unroll
      for (int r = 0; r < 4; ++r) {
        const int s = a * 4 + r;
        float v = fmaf(-0.001953125f, a ? acc1[r] : acc0[r], bkf);  // -2/1024
        bool lt1 = v < bv[s];
        bool lt2 = v < sv[s];
        tv[s] = fminf(fmaxf(v, sv[s]), tv[s]);   // med3
        sv[s] = fminf(fmaxf(v, bv[s]), sv[s]);   // med3
        bv[s] = fminf(v, bv[s]);
        unsigned u1 = (bksk[s] << 16) | (unsigned)k;          // bk=k, sk=old bk
        unsigned u2 = (bksk[s] & 0xFFFFu) | ((unsigned)k << 16); // sk=k
        bksk[s] = lt1 ? u1 : (lt2 ? u2 : bksk[s]);
      }
    }
    __syncthreads();        // next tile landed; all readers done with cur
    cur ^= 1;
  }

  // unpack (epilogue: ah dead, registers plentiful)
  int bk[8], sk[8];
#pragma unroll
  for (int s = 0; s < 8; ++s) { bk[s] = bksk[s] & 0xFFFF; sk[s] = bksk[s] >> 16; }

  // top-3 merge across the 16 col-lanes of each quad (butterfly)
#pragma unroll
  for (int mask = 1; mask < 16; mask <<= 1) {
#pragma unroll
    for (int s = 0; s < 8; ++s) {
      float ov  = __shfl_xor(bv[s], mask);
      float os  = __shfl_xor(sv[s], mask);
      float ot  = __shfl_xor(tv[s], mask);
      int   ok  = __shfl_xor(bk[s], mask);
      int   osk = __shfl_xor(sk[s], mask);
      bool win = (ov < bv[s]) || (ov == bv[s] && ok < bk[s]);
      float a1 = win ? ov : bv[s], a2 = win ? os : sv[s], a3 = win ? ot : tv[s];
      int   a1k = win ? ok : bk[s], a2k = win ? osk : sk[s];
      float b1 = win ? bv[s] : ov, b2 = win ? sv[s] : os;
      int   b1k = win ? bk[s] : ok;
      bool s2 = (a2 < b1) || (a2 == b1 && a2k < b1k);
      bv[s] = a1; bk[s] = a1k;
      sv[s] = s2 ? a2 : b1; sk[s] = s2 ? a2k : b1k;
      tv[s] = s2 ? fminf(a3, b1) : fminf(a2, b2);
    }
  }

  // publish per-(point, half) triples + row ||z||^2
  if (lr == 0) {
#pragma unroll
    for (int a = 0; a < 2; ++a)
#pragma unroll
      for (int r = 0; r < 4; ++r) {
        int s  = a * 4 + r;
        int pt = wp * 32 + a * 16 + quad * 4 + r;
        mv1[pt][h] = bv[s]; mv2[pt][h] = sv[s]; mv3[pt][h] = tv[s];
        mk1[pt][h] = bk[s]; mk2[pt][h] = sk[s];
      }
  }
  if (h == 0 && quad == 0) {
    mz[wp * 32 + lr]      = Szrow[0];
    mz[wp * 32 + 16 + lr] = Szrow[1];
  }
  __syncthreads();

  // merge halves per point (t < 64 == wave 0); codes + flags + loss
  double ls = 0.0;
  if (t < 64) {
    float a1 = mv1[t][0], a2 = mv2[t][0], a3 = mv3[t][0];
    int   a1k = mk1[t][0], a2k = mk2[t][0];
    float c1 = mv1[t][1], c2 = mv2[t][1], c3 = mv3[t][1];
    int   c1k = mk1[t][1], c2k = mk2[t][1];
    bool win = (c1 < a1) || (c1 == a1 && c1k < a1k);
    float x1 = win ? c1 : a1, x2 = win ? c2 : a2, x3 = win ? c3 : a3;
    int   x1k = win ? c1k : a1k, x2k = win ? c2k : a2k;
    float y1 = win ? a1 : c1, y2 = win ? a2 : c2;
    int   y1k = win ? a1k : c1k;
    bool s2 = (x2 < y1) || (x2 == y1 && x2k < y1k);
    float f2v = s2 ? x2 : y1; int f2k = s2 ? x2k : y1k;
    float f3v = s2 ? fminf(x3, y1) : fminf(x2, y2);
    int n = m0 + t;
    codes_out[n] = (float)x1k;
    scodes[t] = x1k;
    float vrowv = mz[t] + x1;       // Sz + approx best: the loss contribution
    ls = (double)vrowv;
    if (f3v - x1 < MARGIN) {
      int pos = atomicAdd(cntf, 1);
      flagf[pos] = n; bvfa[pos] = vrowv;
    } else if (f2v - x1 < MARGIN) {
      int pos = atomicAdd(cnt2, 1);
      flag2[pos] = (unsigned)n | ((unsigned)f2k << 16);
      bv2a[pos] = vrowv;
    }
  }
  if (w == 0) {
    ls += __shfl_down(ls, 32);
    ls += __shfl_down(ls, 16);
    ls += __shfl_down(ls, 8);
    ls += __shfl_down(ls, 4);
    ls += __shfl_down(ls, 2);
    ls += __shfl_down(ls, 1);
    if (t == 0) atomicAdd(&loss_slots[blockIdx.x & 255], ls);
  }
  __syncthreads();

  // fused quantized scatter: 64 rows/block (deferred if block < WSKIP)
  if (m0 >= WSKIP) {
#pragma unroll
    for (int i = 0; i < 16; ++i) {
      int row = i * 4 + w;
      int c = scodes[row];
      *(float4*)(outq + (size_t)(m0 + row) * DIM + l * 4) =
          *(const float4*)(cb + (size_t)c * DIM + l * 4);
    }
  }
}

// Pair fixup: one wave per flagged row; half-wave per candidate code.
// Exact emulation: v = fl32(fl32(Sfl + Bf[k]) - 2*fl32(dot64)); tie -> lower k.
// Loss delta = v_exact(min) - bv2a[i] (bv2a = Sz + approx bv, the value added).
__global__ __launch_bounds__(256) void fixup_pair_kernel(
    const float* __restrict__ z, const float* __restrict__ cb,
    const float* __restrict__ Bf, const unsigned* __restrict__ flag2,
    const int* __restrict__ cnt2, const float* __restrict__ bv2a,
    float* __restrict__ codes_out, float* __restrict__ outq,
    double* __restrict__ loss_slots) {
  const int t   = threadIdx.x;
  const int l   = t & 63;
  const int h   = l >> 5;          // 0 -> bestk, 1 -> seck
  const int sub = l & 31;          // dims sub*8 .. sub*8+7
  const int wid = blockIdx.x * 4 + (t >> 6);
  const int nw  = gridDim.x * 4;
  const int cnt = *cnt2;
  for (int i = wid; i < cnt; i += nw) {
    const unsigned rec = flag2[i];
    const int n  = rec & 0xFFFF;
    const int k2 = rec >> 16;
    const int k1 = (int)codes_out[n];
    const int k  = h ? k2 : k1;
    const float* zr = z + (size_t)n * DIM + sub * 8;
    const float* cr = cb + (size_t)k * DIM + sub * 8;
    const float4 za = *(const float4*)(zr);
    const float4 zb = *(const float4*)(zr + 4);
    const float4 ca = *(const float4*)(cr);
    const float4 cv = *(const float4*)(cr + 4);
    double s = (double)za.x*za.x + (double)za.y*za.y + (double)za.z*za.z + (double)za.w*za.w
             + (double)zb.x*zb.x + (double)zb.y*zb.y + (double)zb.z*zb.z + (double)zb.w*zb.w;
    double d = (double)za.x*ca.x + (double)za.y*ca.y + (double)za.z*ca.z + (double)za.w*ca.w
             + (double)zb.x*cv.x + (double)zb.y*cv.y + (double)zb.z*cv.z + (double)zb.w*cv.w;
#pragma unroll
    for (int m = 1; m < 32; m <<= 1) {
      s += __shfl_xor(s, m);
      d += __shfl_xor(d, m);
    }
    const float Sfl = (float)s;
    const float T1  = Sfl + Bf[k];
    const float v   = T1 - 2.0f * (float)d;
    const float vo  = __shfl_xor(v, 32);
    const int   ko  = __shfl_xor(k, 32);
    const bool keep = (v < vo) || (v == vo && k < ko);
    const float vmin = keep ? v : vo;
    const int   kf   = keep ? k : ko;       // consistent across both halves
    if (l == 0) {
      codes_out[n] = (float)kf;
      atomicAdd(&loss_slots[n & 255], (double)(vmin - bv2a[i]));
    }
    if (kf != k1 && n >= WSKIP)
      *(float4*)(outq + (size_t)n * DIM + l * 4) =
          *(const float4*)(cb + (size_t)kf * DIM + l * 4);
  }
}

// Full rescan for rows with 3+ candidates inside MARGIN (expected ~tens).
// Self-contained: one block per row (grid-stride); wave w scans codes
// [w*256,+256); block writes codes + loss delta + row rewrite directly.
__global__ __launch_bounds__(256) void fixup_full_kernel(
    const float* __restrict__ z, const float* __restrict__ cb,
    const float* __restrict__ Bf, const int* __restrict__ flagf,
    const int* __restrict__ cntf, const float* __restrict__ bvfa,
    float* __restrict__ codes_out, float* __restrict__ outq,
    double* __restrict__ loss_slots) {
  __shared__ float vred[4];
  __shared__ int   kred[4];
  __shared__ int   sfin[2];        // final k, previous k
  const int t = threadIdx.x;
  const int w = t >> 6;
  const int l = t & 63;
  const int cnt = *cntf;
  for (int i = blockIdx.x; i < cnt; i += gridDim.x) {
    const int n = flagf[i];
    const float4 zv = *(const float4*)(z + (size_t)n * DIM + l * 4);
    double s = (double)zv.x*zv.x + (double)zv.y*zv.y
             + (double)zv.z*zv.z + (double)zv.w*zv.w;
#pragma unroll
    for (int off = 32; off > 0; off >>= 1) s += __shfl_xor(s, off);
    const float Sfl = (float)s;
    float bvv = 3.0e38f; int bkk = 0;
    const int kbase = w * 256;
#pragma unroll 4
    for (int k0 = 0; k0 < 256; ++k0) {
      const int k = kbase + k0;
      const float4 cv = *(const float4*)(cb + (size_t)k * DIM + l * 4);
      double d = (double)zv.x*cv.x + (double)zv.y*cv.y
               + (double)zv.z*cv.z + (double)zv.w*cv.w;
#pragma unroll
      for (int off = 32; off > 0; off >>= 1) d += __shfl_xor(d, off);
      float T1 = Sfl + Bf[k];
      float v  = T1 - 2.0f * (float)d;
      if (v < bvv) { bvv = v; bkk = k; }   // ascending k -> lowest on tie
    }
    __syncthreads();
    if (l == 0) { vred[w] = bvv; kred[w] = bkk; }
    __syncthreads();
    if (t == 0) {
      float fv = vred[0]; int fk = kred[0];
#pragma unroll
      for (int j = 1; j < 4; ++j) {
        float v2 = vred[j]; int kk = kred[j];
        if (v2 < fv || (v2 == fv && kk < fk)) { fv = v2; fk = kk; }
      }
      sfin[0] = fk; sfin[1] = (int)codes_out[n];
      codes_out[n] = (float)fk;
      atomicAdd(&loss_slots[n & 255], (double)(fv - bvfa[i]));
    }
    __syncthreads();
    if (sfin[0] != sfin[1] && n >= WSKIP)
      outq[(size_t)n * DIM + t] = cb[(size_t)sfin[0] * DIM + t];
    // next iteration's first __syncthreads orders sfin reuse
  }
}

// Rows [0, WSKIP): scatter cb[codes[n]] (scratch now dead). Last block
// finalizes the loss (all loss writes happened in prior kernels).
__global__ void gather_finalize_kernel(const float* __restrict__ cb,
                                       const float* __restrict__ codes_f,
                                       float* __restrict__ outq,
                                       const double* __restrict__ loss_slots,
                                       float* __restrict__ out_loss) {
  if (blockIdx.x == WSKIP / 4) {     // finalize block
    const int t = threadIdx.x;
    double s = loss_slots[t];
#pragma unroll
    for (int off = 32; off > 0; off >>= 1) s += __shfl_down(s, off);
    __shared__ double ws[4];
    if ((t & 63) == 0) ws[t >> 6] = s;
    __syncthreads();
    if (t == 0) {
      double tot = ws[0] + ws[1] + ws[2] + ws[3];
      out_loss[0] = (float)(1.25 * tot / (double)(N_PTS * (size_t)DIM));
    }
    return;
  }
  int gid = blockIdx.x * 256 + threadIdx.x;
  int n = gid >> 6, l = gid & 63;
  int c = (int)codes_f[n];
  *(float4*)(outq + (size_t)n * DIM + l * 4) =
      *(const float4*)(cb + (size_t)c * DIM + l * 4);
}

extern "C" void kernel_launch(void* const* d_in, const int* in_sizes, int n_in,
                              void* d_out, int out_size, void* d_ws, size_t ws_size,
                              hipStream_t stream) {
  const float* z  = (const float*)d_in[0];
  const float* cb = (const float*)d_in[1];
  float* out = (float*)d_out;
  double* loss_slots = (double*)d_ws;
  int*      cnt2  = (int*)((char*)d_ws + 2048);
  int*      cntf  = (int*)((char*)d_ws + 2052);
  float*    Bf    = (float*)((char*)d_ws + 4096);
  unsigned* flag2 = (unsigned*)((char*)d_ws + 8192);
  short* cbh_perm = (short*)d_out;                                   // [0,512K)
  float* bv2a     = (float*)((char*)d_out + 524288);
  float* bvfa     = (float*)((char*)d_out + 786432);
  int*   flagf    = (int*)((char*)d_out + 1572864);

  prep_cb_kernel<<<K_CODES / 4, 256, 0, stream>>>(
      cb, cbh_perm, Bf, (unsigned long long*)d_ws);
  argmin_mfma_kernel<<<N_PTS / 64, 256, 0, stream>>>(
      z, cb, cbh_perm, Bf, out, out + OUT_VALS, cnt2, cntf, flag2, flagf,
      bv2a, bvfa, loss_slots);
  fixup_pair_kernel<<<1024, 256, 0, stream>>>(
      z, cb, Bf, flag2, cnt2, bv2a, out + OUT_VALS, out, loss_slots);
  fixup_full_kernel<<<2048, 256, 0, stream>>>(
      z, cb, Bf, flagf, cntf, bvfa, out + OUT_VALS, out, loss_slots);
  gather_finalize_kernel<<<WSKIP / 4 + 1, 256, 0, stream>>>(
      cb, out + OUT_VALS, out, loss_slots, out + OUT_VALS + OUT_CODES);
}

// Round 9
// 200.218 us; speedup vs baseline: 1.1878x; 1.1878x over previous
//
#include <hip/hip_runtime.h>

// VQ-VAE vector quantizer, MI355X (gfx950).
// Round 14: consolidation to best-measured pieces.
//  - argmin = r10 structure VERBATIM (16 pts/wave, dbuf global_load_lds,
//    4 blocks/CU, fused scatter+flags; measured 93us, VGPR 52, no spill)
//    + r11's Sz loss fix (vrow = Sz + bestv; bv2a/bvfa store vrow).
//  - fixup_full = r12's measured-good form (4 blocks/row, 64 codes/wave,
//    atomicMin scratch) — r13's 1-block/row serialized 256 latency-chained
//    codes per wave (~21us/row wall) and regressed the "rest" 109->136us.
//  - fixup_write restored; gather_finalize kept merged.
//
// d_out scratch (bytes, consumed before gather_finalize / overwritten later):
//   [0,524288) cbh_perm | [524288,786432) bv2a | [786432,1048576) bvfa
//   [1048576,1572864) ull minkey scratch | [1572864,1835008) flagf
// d_ws: [0,2048) double loss_slots[256]; [2048,2052) cnt2; [2052,2056) cntf;
//       [4096,8192) float Bf[1024]; [8192,270336) uint flag2 (n | seck<<16)

#define N_PTS    65536
#define K_CODES  1024
#define DIM      256
#define MARGIN   1.5e-4f
#define WSKIP    4096

#define OUT_VALS  16777216
#define OUT_CODES 65536

typedef __attribute__((ext_vector_type(8))) short short8v;
typedef __attribute__((ext_vector_type(8))) _Float16 half8v;
typedef __attribute__((ext_vector_type(4))) float float4v;

// perm index (in shorts) for codebook element (r=code, k=dim):
// chunk = ((r>>4)*8 + (k>>5))*4 + ((k>>3)&3); idx = chunk*128 + (r&15)*8 + (k&7)
__device__ __forceinline__ int perm_idx(int r, int k) {
  return ((((r >> 4) * 8 + (k >> 5)) * 4 + ((k >> 3) & 3)) * 128) + (r & 15) * 8 + (k & 7);
}

__device__ __forceinline__ short f2h_bits(float x) {
  union { _Float16 h; short s; } u;
  u.h = (_Float16)x;              // v_cvt_f16_f32, RTE
  return u.s;
}

__device__ __forceinline__ void gload16(const void* g, void* l) {
  __builtin_amdgcn_global_load_lds(
      (const __attribute__((address_space(1))) unsigned*)g,
      (__attribute__((address_space(3))) unsigned*)l, 16, 0, 0);
}

// one wave per code row: Bf[r] = fl32(fp64 sum sq of ORIGINAL cb); emit
// fp16(1024*cb) in B-fragment-permuted order. Init ws header + minkey scratch.
__global__ void prep_cb_kernel(const float* __restrict__ cb,
                               short* __restrict__ cbh_perm,
                               float* __restrict__ Bf,
                               unsigned long long* __restrict__ scratch,
                               unsigned long long* __restrict__ ws0) {
  const int gid = blockIdx.x * 256 + threadIdx.x;
  scratch[gid] = ~0ull;                       // 65536 minkeys
  if (gid < 512) ws0[gid] = 0ull;             // loss_slots + cnt2/cntf
  int r    = blockIdx.x * 4 + (threadIdx.x >> 6);
  int lane = threadIdx.x & 63;
  const float4 v = *(const float4*)(cb + (size_t)r * DIM + lane * 4);
  double s = (double)v.x * v.x + (double)v.y * v.y
           + (double)v.z * v.z + (double)v.w * v.w;
#pragma unroll
  for (int off = 32; off > 0; off >>= 1) s += __shfl_down(s, off);
  if (lane == 0) Bf[r] = (float)s;
  short4 h = make_short4(f2h_bits(v.x * 1024.0f), f2h_bits(v.y * 1024.0f),
                         f2h_bits(v.z * 1024.0f), f2h_bits(v.w * 1024.0f));
  *(short4*)(cbh_perm + perm_idx(r, lane * 4)) = h;   // 8B aligned
}

// 1024 blocks x 256 thr (4 waves). Block: 64 points x all 1024 codes.
// Wave w: 16 points, A-frags resident (fp16). 32-code tiles double-buffered
// in LDS via global_load_lds; one barrier per tile.  (r10 structure, 93us.)
__global__ __launch_bounds__(256, 4) void argmin_mfma_kernel(
    const float* __restrict__ z, const float* __restrict__ cb,
    const short* __restrict__ cbh_perm,
    const float* __restrict__ Bf, float* __restrict__ outq,
    float* __restrict__ codes_out,
    int* __restrict__ cnt2, int* __restrict__ cntf,
    unsigned* __restrict__ flag2, int* __restrict__ flagf,
    float* __restrict__ bv2a, float* __restrict__ bvfa,
    double* __restrict__ loss_slots) {
  __shared__ __align__(16) short lbuf[2][8192];   // 2 x 16 KB tiles
  __shared__ double wls[4];
  const int t    = threadIdx.x;
  const int w    = t >> 6;
  const int l    = t & 63;
  const int quad = l >> 4;
  const int lr   = l & 15;
  const int m0   = blockIdx.x * 64;

  // stage tile 0 early (latency hides under A-frag load/convert)
  {
    const char* src = (const char*)cbh_perm;
    char* dst = (char*)&lbuf[0][0];
#pragma unroll
    for (int i = 0; i < 4; ++i)
      gload16(src + t * 16 + i * 4096, dst + t * 16 + i * 4096);
  }

  // A-fragments: lane holds A[m=lr][k=q*32+quad*8+j], fp16 (z unscaled);
  // fp64 partial sum of squares of this lane's 64 dims of row (w*16+lr).
  half8v ah[8];
  float Szrow;
  {
    const float* zrow = z + (size_t)(m0 + w * 16 + lr) * DIM;
    double zs0 = 0.0, zs1 = 0.0;
#pragma unroll
    for (int q = 0; q < 8; ++q) {
      float4 p0 = *(const float4*)(zrow + q * 32 + quad * 8);
      float4 p1 = *(const float4*)(zrow + q * 32 + quad * 8 + 4);
      zs0 = fma((double)p0.x, (double)p0.x, zs0);
      zs0 = fma((double)p0.y, (double)p0.y, zs0);
      zs0 = fma((double)p0.z, (double)p0.z, zs0);
      zs0 = fma((double)p0.w, (double)p0.w, zs0);
      zs1 = fma((double)p1.x, (double)p1.x, zs1);
      zs1 = fma((double)p1.y, (double)p1.y, zs1);
      zs1 = fma((double)p1.z, (double)p1.z, zs1);
      zs1 = fma((double)p1.w, (double)p1.w, zs1);
      half8v h;
      h[0] = (_Float16)p0.x; h[1] = (_Float16)p0.y;
      h[2] = (_Float16)p0.z; h[3] = (_Float16)p0.w;
      h[4] = (_Float16)p1.x; h[5] = (_Float16)p1.y;
      h[6] = (_Float16)p1.z; h[7] = (_Float16)p1.w;
      ah[q] = h;
    }
    double zs = zs0 + zs1;
    zs += __shfl_xor(zs, 16);      // sum the 4 quad partials (fixed lr)
    zs += __shfl_xor(zs, 32);
    Szrow = (float)zs;             // ||z[m0 + w*16 + (l&15)]||^2
  }

  float bestv[4], secv[4], thirdv[4]; int bestk[4], seck[4];
#pragma unroll
  for (int r = 0; r < 4; ++r) {
    bestv[r] = 3.0e38f; secv[r] = 3.0e38f; thirdv[r] = 3.0e38f;
    bestk[r] = 0; seck[r] = 0;
  }

  __syncthreads();          // tile 0 resident (barrier drains vmcnt)
  int cur = 0;
  for (int it = 0; it < 32; ++it) {
    if (it < 31) {          // prefetch tile it+1 into the other buffer
      const char* src = (const char*)cbh_perm + (size_t)(it + 1) * 16384;
      char* dst = (char*)&lbuf[cur ^ 1][0];
#pragma unroll
      for (int i = 0; i < 4; ++i)
        gload16(src + t * 16 + i * 4096, dst + t * 16 + i * 4096);
    }
    const int c0 = it * 32;
#pragma unroll
    for (int st = 0; st < 2; ++st) {
      float4v acc = {0.f, 0.f, 0.f, 0.f};
#pragma unroll
      for (int q = 0; q < 8; ++q) {
        // B-frag: lane holds B[k=quad*8+j][n=lr] == cb'[n][k]
        half8v b = *(const half8v*)(&lbuf[cur][(st * 8 + q) * 512 + quad * 128 + lr * 8]);
        acc = __builtin_amdgcn_mfma_f32_16x16x32_f16(ah[q], b, acc, 0, 0, 0);
      }
      const int k = c0 + st * 16 + lr;       // this lane's code (C col = lr)
      const float bkf = Bf[k];
#pragma unroll
      for (int r = 0; r < 4; ++r) {          // C row = quad*4 + r (point)
        float v = fmaf(-0.001953125f, acc[r], bkf);   // -2/1024, exact
        bool lt1 = v < bestv[r];
        bool lt2 = v < secv[r];
        thirdv[r] = fminf(fmaxf(v, secv[r]), thirdv[r]);   // med3
        secv[r]   = fminf(fmaxf(v, bestv[r]), secv[r]);    // med3
        bestv[r]  = fminf(v, bestv[r]);
        seck[r]   = lt1 ? bestk[r] : (lt2 ? k : seck[r]);
        bestk[r]  = lt1 ? k : bestk[r];
      }
    }
    __syncthreads();        // next tile landed; all readers done with cur
    cur ^= 1;
  }

  // top-3 merge across the 16 col-lanes of each quad (butterfly)
#pragma unroll
  for (int mask = 1; mask < 16; mask <<= 1) {
#pragma unroll
    for (int r = 0; r < 4; ++r) {
      float ov  = __shfl_xor(bestv[r], mask);
      float os  = __shfl_xor(secv[r], mask);
      float ot  = __shfl_xor(thirdv[r], mask);
      int   ok  = __shfl_xor(bestk[r], mask);
      int   osk = __shfl_xor(seck[r], mask);
      bool win = (ov < bestv[r]) || (ov == bestv[r] && ok < bestk[r]);
      float a1 = win ? ov : bestv[r], a2 = win ? os : secv[r], a3 = win ? ot : thirdv[r];
      int   a1k = win ? ok : bestk[r], a2k = win ? osk : seck[r];
      float b1 = win ? bestv[r] : ov, b2 = win ? secv[r] : os;
      int   b1k = win ? bestk[r] : ok;
      bool s2 = (a2 < b1) || (a2 == b1 && a2k < b1k);
      bestv[r] = a1; bestk[r] = a1k;
      secv[r] = s2 ? a2 : b1; seck[r] = s2 ? a2k : b1k;
      thirdv[r] = s2 ? fminf(a3, b1) : fminf(a2, b2);
    }
  }

  // per-slot row loss values (all lanes active: shfl outside divergence)
  float vrow[4];
#pragma unroll
  for (int r = 0; r < 4; ++r)
    vrow[r] = __shfl(Szrow, quad * 4 + r) + bestv[r];

  // fused quantized scatter (rows < WSKIP deferred: they overlap scratch)
  if (m0 >= WSKIP) {
#pragma unroll
    for (int p = 0; p < 16; ++p) {
      int c = __shfl(bestk[p & 3], (p >> 2) << 4);   // quad (p>>2), slot (p&3)
      int n = m0 + w * 16 + p;
      *(float4*)(outq + (size_t)n * DIM + l * 4) =
          *(const float4*)(cb + (size_t)c * DIM + l * 4);
    }
  }

  // fused loss: sum of vrow over the wave's 16 points
  double ls = 0.0;
  if (lr == 0)
    ls = (double)vrow[0] + (double)vrow[1] + (double)vrow[2] + (double)vrow[3];
  ls += __shfl_down(ls, 16);
  ls += __shfl_down(ls, 32);
  if (l == 0) wls[w] = ls;

  if (lr == 0) {
#pragma unroll
    for (int r = 0; r < 4; ++r) {
      int n = m0 + w * 16 + quad * 4 + r;
      codes_out[n] = (float)bestk[r];
      if (thirdv[r] - bestv[r] < MARGIN) {
        int pos = atomicAdd(cntf, 1);
        flagf[pos] = n; bvfa[pos] = vrow[r];
      } else if (secv[r] - bestv[r] < MARGIN) {
        int pos = atomicAdd(cnt2, 1);
        flag2[pos] = (unsigned)n | ((unsigned)seck[r] << 16);
        bv2a[pos] = vrow[r];
      }
    }
  }
  __syncthreads();
  if (t == 0)
    atomicAdd(&loss_slots[blockIdx.x & 255], wls[0] + wls[1] + wls[2] + wls[3]);
}

// Pair fixup: one wave per flagged row; half-wave per candidate code.
// Exact emulation: v = fl32(fl32(Sfl + Bf[k]) - 2*fl32(dot64)); tie -> lower k.
// Loss delta = v_exact(min) - bv2a[i] (bv2a = Sz + approx bv, the value added).
__global__ __launch_bounds__(256) void fixup_pair_kernel(
    const float* __restrict__ z, const float* __restrict__ cb,
    const float* __restrict__ Bf, const unsigned* __restrict__ flag2,
    const int* __restrict__ cnt2, const float* __restrict__ bv2a,
    float* __restrict__ codes_out, float* __restrict__ outq,
    double* __restrict__ loss_slots) {
  const int t   = threadIdx.x;
  const int l   = t & 63;
  const int h   = l >> 5;          // 0 -> bestk, 1 -> seck
  const int sub = l & 31;          // dims sub*8 .. sub*8+7
  const int wid = blockIdx.x * 4 + (t >> 6);
  const int nw  = gridDim.x * 4;
  const int cnt = *cnt2;
  for (int i = wid; i < cnt; i += nw) {
    const unsigned rec = flag2[i];
    const int n  = rec & 0xFFFF;
    const int k2 = rec >> 16;
    const int k1 = (int)codes_out[n];
    const int k  = h ? k2 : k1;
    const float* zr = z + (size_t)n * DIM + sub * 8;
    const float* cr = cb + (size_t)k * DIM + sub * 8;
    const float4 za = *(const float4*)(zr);
    const float4 zb = *(const float4*)(zr + 4);
    const float4 ca = *(const float4*)(cr);
    const float4 cv = *(const float4*)(cr + 4);
    double s = (double)za.x*za.x + (double)za.y*za.y + (double)za.z*za.z + (double)za.w*za.w
             + (double)zb.x*zb.x + (double)zb.y*zb.y + (double)zb.z*zb.z + (double)zb.w*zb.w;
    double d = (double)za.x*ca.x + (double)za.y*ca.y + (double)za.z*ca.z + (double)za.w*ca.w
             + (double)zb.x*cv.x + (double)zb.y*cv.y + (double)zb.z*cv.z + (double)zb.w*cv.w;
#pragma unroll
    for (int m = 1; m < 32; m <<= 1) {
      s += __shfl_xor(s, m);
      d += __shfl_xor(d, m);
    }
    const float Sfl = (float)s;
    const float T1  = Sfl + Bf[k];
    const float v   = T1 - 2.0f * (float)d;
    const float vo  = __shfl_xor(v, 32);
    const int   ko  = __shfl_xor(k, 32);
    const bool keep = (v < vo) || (v == vo && k < ko);
    const float vmin = keep ? v : vo;
    const int   kf   = keep ? k : ko;       // consistent across both halves
    if (l == 0) {
      codes_out[n] = (float)kf;
      atomicAdd(&loss_slots[n & 255], (double)(vmin - bv2a[i]));
    }
    if (kf != k1 && n >= WSKIP)
      *(float4*)(outq + (size_t)n * DIM + l * 4) =
          *(const float4*)(cb + (size_t)kf * DIM + l * 4);
  }
}

// Full rescan for rows with 3+ candidates inside MARGIN (expected ~tens).
// 4 blocks per row (quarter q); wave handles 64 codes. Cross-block merge via
// atomicMin on (f32-bits<<32 | k); v>0 not required for correct uint order
// here because all candidate v for a row share sign regime near the min --
// and keys are compared only within the same row n.  (r12-measured form.)
__global__ __launch_bounds__(256) void fixup_full_kernel(
    const float* __restrict__ z, const float* __restrict__ cb,
    const float* __restrict__ Bf, const int* __restrict__ flagf,
    const int* __restrict__ cntf, unsigned long long* __restrict__ scratch) {
  __shared__ float vred[4];
  __shared__ int   kred[4];
  const int t = threadIdx.x;
  const int w = t >> 6;
  const int l = t & 63;
  const int cnt = *cntf;
  for (int ib = blockIdx.x; (ib >> 2) < cnt; ib += gridDim.x) {
    const int i = ib >> 2, q = ib & 3;
    const int n = flagf[i];
    const float4 zv = *(const float4*)(z + (size_t)n * DIM + l * 4);
    double s = (double)zv.x*zv.x + (double)zv.y*zv.y
             + (double)zv.z*zv.z + (double)zv.w*zv.w;
#pragma unroll
    for (int off = 32; off > 0; off >>= 1) s += __shfl_xor(s, off);
    const float Sfl = (float)s;
    float bvv = 3.0e38f; int bkk = 0;
    const int kbase = q * 256 + w * 64;
#pragma unroll 4
    for (int k0 = 0; k0 < 64; ++k0) {
      const int k = kbase + k0;
      const float4 cv = *(const float4*)(cb + (size_t)k * DIM + l * 4);
      double d = (double)zv.x*cv.x + (double)zv.y*cv.y
               + (double)zv.z*cv.z + (double)zv.w*cv.w;
#pragma unroll
      for (int off = 32; off > 0; off >>= 1) d += __shfl_xor(d, off);
      float T1 = Sfl + Bf[k];
      float v  = T1 - 2.0f * (float)d;
      if (v < bvv) { bvv = v; bkk = k; }   // ascending k -> lowest on tie
    }
    __syncthreads();
    if (l == 0) { vred[w] = bvv; kred[w] = bkk; }
    __syncthreads();
    if (t == 0) {
      float fv = vred[0]; int fk = kred[0];
#pragma unroll
      for (int j = 1; j < 4; ++j) {
        float v2 = vred[j]; int kk = kred[j];
        if (v2 < fv || (v2 == fv && kk < fk)) { fv = v2; fk = kk; }
      }
      // v is always > 0 here (v ~ ||z-c||^2 with fp32 rounding ~1e-4 <<
      // min distance ~0.5*||z||^2): plain uint order of float bits is
      // monotone for positives.
      unsigned long long key =
          ((unsigned long long)__float_as_uint(fv) << 32) | (unsigned)fk;
      atomicMin(&scratch[n], key);
    }
  }
}

// Resolve full rows: wave per row; codes + loss delta + row rewrite.
__global__ __launch_bounds__(256) void fixup_write_kernel(
    const int* __restrict__ flagf, const int* __restrict__ cntf,
    const unsigned long long* __restrict__ scratch,
    const float* __restrict__ bvfa, const float* __restrict__ cb,
    float* __restrict__ codes_out, float* __restrict__ outq,
    double* __restrict__ loss_slots) {
  const int t = threadIdx.x, l = t & 63;
  const int wid = blockIdx.x * 4 + (t >> 6);
  const int nw  = gridDim.x * 4;
  const int cnt = *cntf;
  for (int i = wid; i < cnt; i += nw) {
    const int n = flagf[i];
    const unsigned long long key = scratch[n];
    const int   fk = (int)(unsigned)(key & 0xFFFFFFFFull);
    const float fv = __uint_as_float((unsigned)(key >> 32));
    const int   k1 = (int)codes_out[n];
    if (l == 0) {
      codes_out[n] = (float)fk;
      atomicAdd(&loss_slots[n & 255], (double)(fv - bvfa[i]));
    }
    if (fk != k1 && n >= WSKIP)
      *(float4*)(outq + (size_t)n * DIM + l * 4) =
          *(const float4*)(cb + (size_t)fk * DIM + l * 4);
  }
}

// Rows [0, WSKIP): scatter cb[codes[n]] (scratch now dead). Block WSKIP/4
// finalizes the loss (all loss deltas applied by prior dispatches).
__global__ void gather_finalize_kernel(const float* __restrict__ cb,
                                       const float* __restrict__ codes_f,
                                       float* __restrict__ outq,
                                       const double* __restrict__ loss_slots,
                                       float* __restrict__ out_loss) {
  if (blockIdx.x == WSKIP / 4) {     // finalize block
    const int t = threadIdx.x;
    double s = loss_slots[t];
#pragma unroll
    for (int off = 32; off > 0; off >>= 1) s += __shfl_down(s, off);
    __shared__ double ws[4];
    if ((t & 63) == 0) ws[t >> 6] = s;
    __syncthreads();
    if (t == 0) {
      double tot = ws[0] + ws[1] + ws[2] + ws[3];
      out_loss[0] = (float)(1.25 * tot / (double)(N_PTS * (size_t)DIM));
    }
    return;
  }
  int gid = blockIdx.x * 256 + threadIdx.x;
  int n = gid >> 6, l = gid & 63;
  int c = (int)codes_f[n];
  *(float4*)(outq + (size_t)n * DIM + l * 4) =
      *(const float4*)(cb + (size_t)c * DIM + l * 4);
}

extern "C" void kernel_launch(void* const* d_in, const int* in_sizes, int n_in,
                              void* d_out, int out_size, void* d_ws, size_t ws_size,
                              hipStream_t stream) {
  const float* z  = (const float*)d_in[0];
  const float* cb = (const float*)d_in[1];
  float* out = (float*)d_out;
  double* loss_slots = (double*)d_ws;
  int*      cnt2  = (int*)((char*)d_ws + 2048);
  int*      cntf  = (int*)((char*)d_ws + 2052);
  float*    Bf    = (float*)((char*)d_ws + 4096);
  unsigned* flag2 = (unsigned*)((char*)d_ws + 8192);
  short* cbh_perm = (short*)d_out;                                   // [0,512K)
  float* bv2a     = (float*)((char*)d_out + 524288);
  float* bvfa     = (float*)((char*)d_out + 786432);
  unsigned long long* scratch = (unsigned long long*)((char*)d_out + 1048576);
  int*   flagf    = (int*)((char*)d_out + 1572864);

  prep_cb_kernel<<<K_CODES / 4, 256, 0, stream>>>(
      cb, cbh_perm, Bf, scratch, (unsigned long long*)d_ws);
  argmin_mfma_kernel<<<N_PTS / 64, 256, 0, stream>>>(
      z, cb, cbh_perm, Bf, out, out + OUT_VALS, cnt2, cntf, flag2, flagf,
      bv2a, bvfa, loss_slots);
  fixup_pair_kernel<<<1024, 256, 0, stream>>>(
      z, cb, Bf, flag2, cnt2, bv2a, out + OUT_VALS, out, loss_slots);
  fixup_full_kernel<<<2048, 256, 0, stream>>>(z, cb, Bf, flagf, cntf, scratch);
  fixup_write_kernel<<<64, 256, 0, stream>>>(
      flagf, cntf, scratch, bvfa, cb, out + OUT_VALS, out, loss_slots);
  gather_finalize_kernel<<<WSKIP / 4 + 1, 256, 0, stream>>>(
      cb, out + OUT_VALS, out, loss_slots, out + OUT_VALS + OUT_CODES);
}